// Round 8
// baseline (307.356 us; speedup 1.0000x reference)
//
#include <hip/hip_runtime.h>
#include <hip/hip_bf16.h>
#include <math.h>

#define NPTS   500000
#define NB     256
#define TOPK   10
#define CAP    2048        // per-query candidate cap in final phase
#define GRID   512         // 2 blocks/CU x 256 CU: all blocks co-resident BY
                           // CONSTRUCTION (launch_bounds(256,2) caps VGPR=256,
                           // LDS 17.5KB/block) -> software barrier is safe
#define SBLK   1024        // sample slices (R3 geometry: tau bitwise-identical)
#define SPER   16          // points per slice -> 16384-pt sample
#define MARGIN 2.0f        // bf16 dot err <~0.5; 4x headroom
#define NWCH   15625       // 500000 / 32: chunks of 32 points (exact!)
#define NSEG   2           // GRID / 256: posq segments read by final phase
#define LCAP   8           // per-(block,query) local cap; overflow safe-path
#define PMAIN  393216      // main pair region (dwords) < 2^20
#define OCAP   32768       // overflow pair region (dwords)

typedef short v2s  __attribute__((ext_vector_type(2)));
typedef short v4s  __attribute__((ext_vector_type(4)));
typedef short v8s  __attribute__((ext_vector_type(8)));
typedef float v16f __attribute__((ext_vector_type(16)));

__device__ __forceinline__ unsigned short f2bf(float f) {   // RNE
    unsigned u = __float_as_uint(f);
    unsigned r = u + 0x7FFFu + ((u >> 16) & 1u);
    return (unsigned short)(r >> 16);
}
// packed f32x2 -> bf16x2 (hw cvt, RNE; lo short = f.x). memcpy-pun: legal & proven.
__device__ __forceinline__ v2s pk2(float2 f) {
    __hip_bfloat162 h = __float22bfloat162_rn(f);
    v2s r;
    __builtin_memcpy(&r, &h, 4);
    return r;
}

// --- exact fp32 pieces: bitwise-identical order in sample and final ---------
__device__ __forceinline__ float norm34(const float* __restrict__ r) {
    float a0 = 0.f, a1 = 0.f, a2 = 0.f, a3 = 0.f;
#pragma unroll
    for (int d = 0; d < 32; d += 4) {
        a0 = fmaf(r[d + 0], r[d + 0], a0);
        a1 = fmaf(r[d + 1], r[d + 1], a1);
        a2 = fmaf(r[d + 2], r[d + 2], a2);
        a3 = fmaf(r[d + 3], r[d + 3], a3);
    }
    a0 = fmaf(r[32], r[32], a0);
    a1 = fmaf(r[33], r[33], a1);
    return (a0 + a1) + (a2 + a3);
}
__device__ __forceinline__ float dot34(const float* __restrict__ r, const float* q) {
    float a0 = 0.f, a1 = 0.f, a2 = 0.f, a3 = 0.f;
#pragma unroll
    for (int d = 0; d < 32; d += 4) {
        a0 = fmaf(r[d + 0], q[d + 0], a0);
        a1 = fmaf(r[d + 1], q[d + 1], a1);
        a2 = fmaf(r[d + 2], q[d + 2], a2);
        a3 = fmaf(r[d + 3], q[d + 3], a3);
    }
    a0 = fmaf(r[32], q[32], a0);
    a1 = fmaf(r[33], q[33], a1);
    return (a0 + a1) + (a2 + a3);
}
// float4 LDS variant, IDENTICAL fma order -> bitwise-equal s
__device__ __forceinline__ float dot34_v4(const float4* __restrict__ r4, const float* q) {
    float a0 = 0.f, a1 = 0.f, a2 = 0.f, a3 = 0.f;
#pragma unroll
    for (int dp = 0; dp < 8; ++dp) {
        float4 v = r4[dp];
        a0 = fmaf(v.x, q[4 * dp + 0], a0);
        a1 = fmaf(v.y, q[4 * dp + 1], a1);
        a2 = fmaf(v.z, q[4 * dp + 2], a2);
        a3 = fmaf(v.w, q[4 * dp + 3], a3);
    }
    float2 t = *(const float2*)(r4 + 8);
    a0 = fmaf(t.x, q[32], a0);
    a1 = fmaf(t.y, q[33], a1);
    return (a0 + a1) + (a2 + a3);
}
__device__ __forceinline__ void load_q(const float* __restrict__ obs,
                                       const float* __restrict__ act, int b, float* q) {
#pragma unroll
    for (int d = 0; d < 32; ++d) q[d] = obs[b * 32 + d];
    q[32] = act[b * 2 + 0];
    q[33] = act[b * 2 + 1];
}
// this lane's 9 float2 pieces of one msa row (half-split K dims + dims 32/33)
__device__ __forceinline__ void load9(float2* __restrict__ e,
                                      const float* __restrict__ rp, int half) {
    e[0] = *(const float2*)(rp + half * 8 + 0);
    e[1] = *(const float2*)(rp + half * 8 + 2);
    e[2] = *(const float2*)(rp + half * 8 + 4);
    e[3] = *(const float2*)(rp + half * 8 + 6);
    e[4] = *(const float2*)(rp + 16 + half * 8 + 0);
    e[5] = *(const float2*)(rp + 16 + half * 8 + 2);
    e[6] = *(const float2*)(rp + 16 + half * 8 + 4);
    e[7] = *(const float2*)(rp + 16 + half * 8 + 6);
    e[8] = *(const float2*)(rp + 32);
}

// --- software grid barrier (all GRID blocks co-resident by construction) ----
// R7 bug: spinning with atomicAdd(cnt,0) is a device-scope RMW -> 512 waves
// fight for EXCLUSIVE ownership of one line (~1M RMWs, +28MB FETCH, arrivals
// queue behind spinners). Fix: ONE RMW to arrive, then spin on a device-scope
// atomic LOAD (coherent read, no ownership transfer), throttled by s_sleep.
__device__ __forceinline__ void gsync(int* cnt) {
    __syncthreads();
    if (threadIdx.x == 0) {
        __threadfence();                        // release
        atomicAdd(cnt, 1);                      // arrive (single RMW)
        while (__hip_atomic_load(cnt, __ATOMIC_RELAXED,
                                 __HIP_MEMORY_SCOPE_AGENT) < GRID)
            __builtin_amdgcn_s_sleep(2);
        __threadfence();                        // acquire
    }
    __syncthreads();
}

// --- phase-overlaid LDS layouts (aliased; phases separated by gsync) --------
struct SmSample { float sm[SPER * 36]; float smn[SPER]; };           // ~2.4 KB
struct SmTau    { unsigned short qs[48]; };                          // 96 B
struct SmFilter { int lcount[NB]; int lcand[NB * LCAP]; int gbase; };// ~9.2 KB
struct SmFinal  { float ls[CAP]; int li[CAP]; int sc[NB]; int lcnt;
                  float rs[4]; int ri[4];
                  float sel_s[TOPK]; int sel_i[TOPK]; };             // ~17.5 KB

// tiny init: zero cursor (2 ints @ws+0) and barrier counters (@ws+64,128,192)
__global__ void k_init(int* wsi) {
    const int t = threadIdx.x;
    if (t < 64) wsi[t] = 0;                      // first 256 B of ws
}

// === ONE plain kernel: sample -> tau -> filter -> final (software barriers) =
// Identical to the PASSING R7 kernel except gsync (single-variable A/B).
__global__ __launch_bounds__(256, 2) void k_mega(const float* __restrict__ obs,
                                                 const float* __restrict__ act,
                                                 const float* __restrict__ msa,
                                                 const float* __restrict__ memQ,
                                                 int* __restrict__ cursor,
                                                 int* __restrict__ bars,
                                                 v8s* __restrict__ afrag,
                                                 float* __restrict__ minima,
                                                 int* __restrict__ posq,
                                                 unsigned* __restrict__ pbuf,
                                                 float* __restrict__ out) {
    __shared__ __align__(16) char smraw[17536];
    const int g = blockIdx.x, t = threadIdx.x;

    // ---- P0: sample — block g owns slices 2g, 2g+1 (R3 geometry) -----------
    {
        SmSample& S = *reinterpret_cast<SmSample*>(smraw);
        float q[34];
        load_q(obs, act, t, q);                 // t = query id
#pragma unroll 1
        for (int sl = 0; sl < 2; ++sl) {
            const int slice = g * 2 + sl;       // 0..1023
            const int base = slice * SPER;
            for (int i = t; i < SPER * 34; i += 256) {
                int row = i / 34, d = i - row * 34;
                S.sm[row * 36 + d] = msa[(size_t)base * 34 + i];
            }
            __syncthreads();
            if (t < SPER) S.smn[t] = norm34(&S.sm[t * 36]);
            __syncthreads();
            float best = __builtin_inff();
#pragma unroll
            for (int j = 0; j < SPER; ++j) {
                float s = fmaf(-2.f, dot34_v4((const float4*)&S.sm[j * 36], q), S.smn[j]);
                best = fminf(best, s);
            }
            minima[(size_t)t * SBLK + slice] = best;
            __syncthreads();                    // sm reused next slice
        }
    }
    gsync(bars + 0);

    // ---- P1: tau (R3 k_tau verbatim; wave 0 of blocks g<NB) + A-frag pack --
    if (g < NB) {
        SmTau& T = *reinterpret_cast<SmTau*>(smraw);
        if (t < 64) {
            const int lane = t;
            float v[16];
#pragma unroll
            for (int k = 0; k < 16; ++k) v[k] = minima[(size_t)g * SBLK + lane + 64 * k];
            float last = 0.f;
            for (int r = 0; r < TOPK; ++r) {
                float lm = v[0]; int la = 0;
#pragma unroll
                for (int k = 1; k < 16; ++k) { if (v[k] < lm) { lm = v[k]; la = k; } }
                float wm = lm;
                for (int off = 32; off; off >>= 1) wm = fminf(wm, __shfl_xor(wm, off));
                unsigned long long msk = __ballot(lm == wm);
                int first = (int)__builtin_ctzll(msk);
                if (lane == first) {
#pragma unroll
                    for (int k = 0; k < 16; ++k) { if (k == la) v[k] = __builtin_inff(); }
                }
                last = wm;                      // wave-uniform
            }
            // q-hat = [q(34), -0.5, (tau+MARGIN)/2, 0..0] as bf16 in LDS
            float val = 0.f;
            if (lane < 32)       val = obs[g * 32 + lane];
            else if (lane < 34)  val = act[g * 2 + (lane - 32)];
            else if (lane == 34) val = -0.5f;
            else if (lane == 35) val = 0.5f * (last + MARGIN);
            if (lane < 48) T.qs[lane] = (lane < 36) ? f2bf(val) : (unsigned short)0;
        }
        __syncthreads();
        if (t < 6) {                            // pack A-frags for query row g
            int s = t >> 1, half = t & 1;
            int qt = g >> 5, mrow = g & 31;
            v8s frag = *(const v8s*)&T.qs[s * 16 + half * 8];
            afrag[(qt * 3 + s) * 64 + half * 32 + mrow] = frag;
        }
    }
    gsync(bars + 1);

    // ---- P2: MFMA bf16 filter — R3 core VERBATIM (identical geometry) ------
    {
        SmFilter& F = *reinterpret_cast<SmFilter*>(smraw);
        const int w = t >> 6, lane = t & 63;
        const int mrow = lane & 31, half = lane >> 5;
        v8s A[8][3];
#pragma unroll
        for (int qt = 0; qt < 8; ++qt)
#pragma unroll
            for (int s = 0; s < 3; ++s)
                A[qt][s] = afrag[(qt * 3 + s) * 64 + lane];
        F.lcount[t] = 0;
        __syncthreads();
        const v16f zacc = (v16f)0.0f;
        const int gw = g * 4 + w;               // global wave id, < 2048
        const int step = GRID * 4;              // 2048 (same as R3)

        auto process = [&](const float2* c, int wc) {
            const int p0 = wc * 32 + mrow;
            float n0 = 0.f, n1 = 0.f;
            n0 = fmaf(c[0].x, c[0].x, n0); n1 = fmaf(c[0].y, c[0].y, n1);
            n0 = fmaf(c[1].x, c[1].x, n0); n1 = fmaf(c[1].y, c[1].y, n1);
            n0 = fmaf(c[2].x, c[2].x, n0); n1 = fmaf(c[2].y, c[2].y, n1);
            n0 = fmaf(c[3].x, c[3].x, n0); n1 = fmaf(c[3].y, c[3].y, n1);
            n0 = fmaf(c[4].x, c[4].x, n0); n1 = fmaf(c[4].y, c[4].y, n1);
            n0 = fmaf(c[5].x, c[5].x, n0); n1 = fmaf(c[5].y, c[5].y, n1);
            n0 = fmaf(c[6].x, c[6].x, n0); n1 = fmaf(c[6].y, c[6].y, n1);
            n0 = fmaf(c[7].x, c[7].x, n0); n1 = fmaf(c[7].y, c[7].y, n1);
            float part = n0 + n1;
            part = fmaf(c[8].x, c[8].x * 0.5f, part);
            part = fmaf(c[8].y, c[8].y * 0.5f, part);
            float nrm = part + __shfl_xor(part, 32);
            float thr = 0.5f * nrm;             // hit iff acc >= thr
            v4s b0lo = __builtin_shufflevector(pk2(c[0]), pk2(c[1]), 0, 1, 2, 3);
            v4s b0hi = __builtin_shufflevector(pk2(c[2]), pk2(c[3]), 0, 1, 2, 3);
            v8s B0 = __builtin_shufflevector(b0lo, b0hi, 0, 1, 2, 3, 4, 5, 6, 7);
            v4s b1lo = __builtin_shufflevector(pk2(c[4]), pk2(c[5]), 0, 1, 2, 3);
            v4s b1hi = __builtin_shufflevector(pk2(c[6]), pk2(c[7]), 0, 1, 2, 3);
            v8s B1 = __builtin_shufflevector(b1lo, b1hi, 0, 1, 2, 3, 4, 5, 6, 7);
            v8s B2 = (v8s)(short)0;
            if (half == 0) {
                v2s m33 = pk2(c[8]);
                B2[0] = m33[0];                 // m32 (k=32)
                B2[1] = m33[1];                 // m33 (k=33)
                B2[3] = (short)0x3F80;          // k=35: 1.0 pairs q's tau-term
            }                                   // k=34 stays 0 (pairs q's -0.5)
#pragma unroll
            for (int qt = 0; qt < 8; ++qt) {
                v16f acc = __builtin_amdgcn_mfma_f32_32x32x16_bf16(A[qt][0], B0, zacc, 0, 0, 0);
                acc = __builtin_amdgcn_mfma_f32_32x32x16_bf16(A[qt][1], B1, acc, 0, 0, 0);
                acc = __builtin_amdgcn_mfma_f32_32x32x16_bf16(A[qt][2], B2, acc, 0, 0, 0);
                float m0 = fmaxf(fmaxf(acc[0], acc[1]), acc[2]);
                float m1 = fmaxf(fmaxf(acc[3], acc[4]), acc[5]);
                float m2 = fmaxf(fmaxf(acc[6], acc[7]), acc[8]);
                float m3 = fmaxf(fmaxf(acc[9], acc[10]), acc[11]);
                float m4 = fmaxf(fmaxf(acc[12], acc[13]), acc[14]);
                float mx = fmaxf(fmaxf(fmaxf(m0, m1), m2),
                                 fmaxf(fmaxf(m3, m4), acc[15]));
                if (mx >= thr) {
                    unsigned hm = 0;
#pragma unroll
                    for (int r = 0; r < 16; ++r) hm |= (acc[r] >= thr) ? (1u << r) : 0u;
                    while (hm) {                // rare per lane
                        int r = __builtin_ctz(hm);
                        hm &= hm - 1;
                        int qq = qt * 32 + (r & 3) + 8 * (r >> 2) + 4 * half;
                        int slot = atomicAdd(&F.lcount[qq], 1);
                        if (slot < LCAP) F.lcand[qq * LCAP + slot] = p0;
                        else {                  // SAFE overflow: side region
                            int dg = atomicAdd(cursor + 1, 1);
                            if (dg < OCAP) pbuf[PMAIN + dg] = ((unsigned)qq << 19) | (unsigned)p0;
                        }
                    }
                }
            }
        };

        float2 bufA[9], bufB[9];
        int wc = gw;
        load9(bufA, msa + (size_t)(wc * 32 + mrow) * 34, half);   // prologue
#pragma unroll 1
        for (;;) {
            const int w1 = wc + step;
            {
                const int pn = (w1 < NWCH) ? w1 : gw;
                load9(bufB, msa + (size_t)(pn * 32 + mrow) * 34, half);
            }
            __builtin_amdgcn_sched_barrier(0);
            process(bufA, wc);
            wc = w1;
            if (wc >= NWCH) break;
            const int w2 = wc + step;
            {
                const int pn = (w2 < NWCH) ? w2 : gw;
                load9(bufA, msa + (size_t)(pn * 32 + mrow) * 34, half);
            }
            __builtin_amdgcn_sched_barrier(0);
            process(bufB, wc);
            wc = w2;
            if (wc >= NWCH) break;
        }
        __syncthreads();
        // flush: prefix-scan -> ONE cursor atomic -> compacted writes + pos
        int n = F.lcount[t];
        if (n > LCAP) n = LCAP;
        F.lcount[t] = n;
        __syncthreads();
        for (int off = 1; off < 256; off <<= 1) {
            int v = (t >= off) ? F.lcount[t - off] : 0;
            __syncthreads();
            F.lcount[t] += v;
            __syncthreads();
        }
        int base_l = F.lcount[t] - n;
        if (t == 255) F.gbase = atomicAdd(cursor, F.lcount[255]);
        __syncthreads();
        int start = F.gbase + base_l;
        if (start >= PMAIN) { start = 0; n = 0; }
        else if (start + n > PMAIN) n = PMAIN - start;
        posq[g * NB + t] = start | (n << 20);
        for (int i = 0; i < n; ++i)
            pbuf[start + i] = (unsigned)F.lcand[t * LCAP + i];
    }
    gsync(bars + 2);

    // ---- P3: final — R3 k_final verbatim (blocks g<NB) ---------------------
    if (g < NB) {
        SmFinal& F = *reinterpret_cast<SmFinal*>(smraw);
        const int b = g;
        const int lane = t & 63, wid = t >> 6;
        int nk[NSEG], pk6[NSEG], tot = 0;
#pragma unroll
        for (int k = 0; k < NSEG; ++k) {
            int packed = posq[(size_t)(t + 256 * k) * NB + b];
            nk[k] = (packed >> 20) & 0xF;
            pk6[k] = packed & 0xFFFFF;
            tot += nk[k];
        }
        F.sc[t] = tot;
        __syncthreads();
        for (int off = 1; off < 256; off <<= 1) {
            int v = (t >= off) ? F.sc[t - off] : 0;
            __syncthreads();
            F.sc[t] += v;
            __syncthreads();
        }
        int myoff = F.sc[t] - tot;
        if (t == 0) F.lcnt = (F.sc[255] > CAP) ? CAP : F.sc[255];
        __syncthreads();
#pragma unroll
        for (int k = 0; k < NSEG; ++k)
            for (int i = 0; i < nk[k]; ++i) {
                if (myoff < CAP) F.li[myoff] = (int)pbuf[pk6[k] + i];
                ++myoff;
            }
        int novf = cursor[1];
        if (novf > OCAP) novf = OCAP;
        for (int j = t; j < novf; j += 256) {
            unsigned pr = pbuf[PMAIN + j];
            if ((int)(pr >> 19) == b) {
                int s = atomicAdd(&F.lcnt, 1);
                if (s < CAP) F.li[s] = (int)(pr & 0x7FFFFu);
            }
        }
        __syncthreads();
        int cnt = F.lcnt;
        if (cnt > CAP) cnt = CAP;
        float q[34];
        load_q(obs, act, b, q);
        for (int j = t; j < cnt; j += 256) {
            const float* row = msa + (size_t)F.li[j] * 34;
            F.ls[j] = fmaf(-2.f, dot34(row, q), norm34(row));
        }
        __syncthreads();
        for (int k = 0; k < TOPK; ++k) {
            float bs = __builtin_inff();
            int   bi = 0x7fffffff;
            for (int j = t; j < cnt; j += 256) {
                float s = F.ls[j]; int i = F.li[j];
                if (s < bs || (s == bs && i < bi)) { bs = s; bi = i; }
            }
            for (int off = 32; off; off >>= 1) {
                float s2 = __shfl_down(bs, off);
                int   i2 = __shfl_down(bi, off);
                if (s2 < bs || (s2 == bs && i2 < bi)) { bs = s2; bi = i2; }
            }
            if (lane == 0) { F.rs[wid] = bs; F.ri[wid] = bi; }
            __syncthreads();
            if (t == 0) {
                float fs = F.rs[0]; int fi = F.ri[0];
#pragma unroll
                for (int ww = 1; ww < 4; ++ww) {
                    if (F.rs[ww] < fs || (F.rs[ww] == fs && F.ri[ww] < fi)) { fs = F.rs[ww]; fi = F.ri[ww]; }
                }
                F.sel_s[k] = fs; F.sel_i[k] = fi;
            }
            __syncthreads();
            const int win = F.sel_i[k];
            for (int j = t; j < cnt; j += 256) {
                if (F.li[j] == win) F.ls[j] = __builtin_inff();
            }
            __syncthreads();
        }
        if (t == 0) {
            float m = F.sel_s[TOPK - 1];
            float wsum = 0.f, acc = 0.f;
#pragma unroll
            for (int k = 0; k < TOPK; ++k) {
                if (F.sel_i[k] == 0x7fffffff) continue;
                float w2 = expf(F.sel_s[k] - m);
                wsum += w2;
                acc = fmaf(w2, memQ[F.sel_i[k]], acc);
            }
            out[b] = acc / wsum;
        }
    }
}

extern "C" void kernel_launch(void* const* d_in, const int* in_sizes, int n_in,
                              void* d_out, int out_size, void* d_ws, size_t ws_size,
                              hipStream_t stream) {
    const float* obs = (const float*)d_in[0];   // [256,32]
    const float* act = (const float*)d_in[1];   // [256,2]
    const float* msa = (const float*)d_in[2];   // [500000,34]
    const float* mq  = (const float*)d_in[3];   // [500000,1]
    float* out = (float*)d_out;                 // [256]

    char* ws = (char*)d_ws;
    int*      wsi    = (int*)ws;                            // ints 0..63
    int*      cursor = (int*)ws;                            // [0..1]
    int*      bars   = (int*)(ws + 64);                     // bars[0..2] @ +64B
    v8s*      afrag  = (v8s*)(ws + 256);                    // 24576 B
    float*    minima = (float*)(ws + 32768);                // 1 MB (256 x 1024)
    int*      posq   = (int*)(ws + 32768 + 1048576);        // 512 KB used
    unsigned* pbuf   = (unsigned*)(ws + 32768 + 1048576 + 1572864); // 1703936 B
    // total ws use ~4.3 MB

    k_init<<<1, 64, 0, stream>>>(wsi);
    k_mega<<<GRID, 256, 0, stream>>>(obs, act, msa, mq, cursor, bars,
                                     afrag, minima, posq, pbuf, out);
}

// Round 9
// 169.921 us; speedup vs baseline: 1.8088x; 1.8088x over previous
//
#include <hip/hip_runtime.h>
#include <hip/hip_bf16.h>
#include <math.h>

#define NPTS   500000
#define NB     256
#define TOPK   10
#define CAP    2048        // per-query candidate cap in k_final
#define SBLK   1024        // sample slices
#define SPER   16          // points per slice -> 16384-pt sample
#define MARGIN 2.0f        // bf16 dot err <~0.5; 4x headroom
#define NWCH   15625       // 500000 / 32: wave-chunks of 32 points (exact!)
#define FBLK   512         // k_filter grid: 2 blocks/CU resident, ONE round
#define NSEG   2           // FBLK / 256: posq segments read by k_final
#define LCAP   8           // per-(block,query) local cap; overflow safe-path
#define PMAIN  393216      // main pair region (dwords) < 2^20
#define OCAP   32768       // overflow pair region (dwords)

typedef short v2s  __attribute__((ext_vector_type(2)));
typedef short v4s  __attribute__((ext_vector_type(4)));
typedef short v8s  __attribute__((ext_vector_type(8)));
typedef float v16f __attribute__((ext_vector_type(16)));

__device__ __forceinline__ unsigned short f2bf(float f) {   // RNE
    unsigned u = __float_as_uint(f);
    unsigned r = u + 0x7FFFu + ((u >> 16) & 1u);
    return (unsigned short)(r >> 16);
}
// packed f32x2 -> bf16x2 (hw cvt, RNE; lo short = f.x). memcpy-pun: legal & proven.
__device__ __forceinline__ v2s pk2(float2 f) {
    __hip_bfloat162 h = __float22bfloat162_rn(f);
    v2s r;
    __builtin_memcpy(&r, &h, 4);
    return r;
}

// --- exact fp32 pieces: bitwise-identical order in k_sample and k_final -----
__device__ __forceinline__ float norm34(const float* __restrict__ r) {
    float a0 = 0.f, a1 = 0.f, a2 = 0.f, a3 = 0.f;
#pragma unroll
    for (int d = 0; d < 32; d += 4) {
        a0 = fmaf(r[d + 0], r[d + 0], a0);
        a1 = fmaf(r[d + 1], r[d + 1], a1);
        a2 = fmaf(r[d + 2], r[d + 2], a2);
        a3 = fmaf(r[d + 3], r[d + 3], a3);
    }
    a0 = fmaf(r[32], r[32], a0);
    a1 = fmaf(r[33], r[33], a1);
    return (a0 + a1) + (a2 + a3);
}
__device__ __forceinline__ float dot34(const float* __restrict__ r, const float* q) {
    float a0 = 0.f, a1 = 0.f, a2 = 0.f, a3 = 0.f;
#pragma unroll
    for (int d = 0; d < 32; d += 4) {
        a0 = fmaf(r[d + 0], q[d + 0], a0);
        a1 = fmaf(r[d + 1], q[d + 1], a1);
        a2 = fmaf(r[d + 2], q[d + 2], a2);
        a3 = fmaf(r[d + 3], q[d + 3], a3);
    }
    a0 = fmaf(r[32], q[32], a0);
    a1 = fmaf(r[33], q[33], a1);
    return (a0 + a1) + (a2 + a3);
}
// float4 LDS variant, IDENTICAL fma order -> bitwise-equal s
__device__ __forceinline__ float dot34_v4(const float4* __restrict__ r4, const float* q) {
    float a0 = 0.f, a1 = 0.f, a2 = 0.f, a3 = 0.f;
#pragma unroll
    for (int dp = 0; dp < 8; ++dp) {
        float4 v = r4[dp];
        a0 = fmaf(v.x, q[4 * dp + 0], a0);
        a1 = fmaf(v.y, q[4 * dp + 1], a1);
        a2 = fmaf(v.z, q[4 * dp + 2], a2);
        a3 = fmaf(v.w, q[4 * dp + 3], a3);
    }
    float2 t = *(const float2*)(r4 + 8);
    a0 = fmaf(t.x, q[32], a0);
    a1 = fmaf(t.y, q[33], a1);
    return (a0 + a1) + (a2 + a3);
}
__device__ __forceinline__ void load_q(const float* __restrict__ obs,
                                       const float* __restrict__ act, int b, float* q) {
#pragma unroll
    for (int d = 0; d < 32; ++d) q[d] = obs[b * 32 + d];
    q[32] = act[b * 2 + 0];
    q[33] = act[b * 2 + 1];
}
// this lane's 9 float2 pieces of one msa row (half-split K dims + dims 32/33)
__device__ __forceinline__ void load9(float2* __restrict__ e,
                                      const float* __restrict__ rp, int half) {
    e[0] = *(const float2*)(rp + half * 8 + 0);
    e[1] = *(const float2*)(rp + half * 8 + 2);
    e[2] = *(const float2*)(rp + half * 8 + 4);
    e[3] = *(const float2*)(rp + half * 8 + 6);
    e[4] = *(const float2*)(rp + 16 + half * 8 + 0);
    e[5] = *(const float2*)(rp + 16 + half * 8 + 2);
    e[6] = *(const float2*)(rp + 16 + half * 8 + 4);
    e[7] = *(const float2*)(rp + 16 + half * 8 + 6);
    e[8] = *(const float2*)(rp + 32);
}

// --- kernel 0a: per-(query, 16-pt slice) min of s; minima transposed --------
__global__ __launch_bounds__(256, 4) void k_sample(const float* __restrict__ obs,
                                                   const float* __restrict__ act,
                                                   const float* __restrict__ msa,
                                                   float* __restrict__ minima) {
    __shared__ __align__(16) float sm[SPER * 36];
    __shared__ float smn[SPER];
    const int g = blockIdx.x, t = threadIdx.x;
    const int base = g * SPER;
    for (int i = t; i < SPER * 34; i += 256) {
        int row = i / 34, d = i - row * 34;
        sm[row * 36 + d] = msa[(size_t)base * 34 + i];
    }
    __syncthreads();
    if (t < SPER) smn[t] = norm34(&sm[t * 36]);
    __syncthreads();
    float q[34];
    load_q(obs, act, t, q);
    float best = __builtin_inff();
#pragma unroll
    for (int j = 0; j < SPER; ++j) {
        float s = fmaf(-2.f, dot34_v4((const float4*)&sm[j * 36], q), smn[j]);
        best = fminf(best, s);
    }
    minima[(size_t)t * SBLK + g] = best;          // transposed: k_tau coalesced
}

// --- kernel 0b: tau = 10th-smallest slice-min; pack A-frags; zero cursors ---
__global__ __launch_bounds__(64) void k_tau(const float* __restrict__ minima,
                                            const float* __restrict__ obs,
                                            const float* __restrict__ act,
                                            v8s* __restrict__ afrag,
                                            int* __restrict__ cursor) {
    __shared__ __align__(16) unsigned short qs[48];
    const int b = blockIdx.x, lane = threadIdx.x;
    if (b == 0 && lane == 0) { cursor[0] = 0; cursor[1] = 0; }
    float v[16];
#pragma unroll
    for (int k = 0; k < 16; ++k) v[k] = minima[(size_t)b * SBLK + lane + 64 * k];
    float last = 0.f;
    for (int r = 0; r < TOPK; ++r) {
        float lm = v[0]; int la = 0;
#pragma unroll
        for (int k = 1; k < 16; ++k) { if (v[k] < lm) { lm = v[k]; la = k; } }
        float wm = lm;
        for (int off = 32; off; off >>= 1) wm = fminf(wm, __shfl_xor(wm, off));
        unsigned long long msk = __ballot(lm == wm);
        int first = (int)__builtin_ctzll(msk);
        if (lane == first) {
#pragma unroll
            for (int k = 0; k < 16; ++k) { if (k == la) v[k] = __builtin_inff(); }
        }
        last = wm;   // wave-uniform
    }
    // q-hat = [q(34), -0.5, (tau+MARGIN)/2, 0..0] as bf16 in LDS
    float val = 0.f;
    if (lane < 32)       val = obs[b * 32 + lane];
    else if (lane < 34)  val = act[b * 2 + (lane - 32)];
    else if (lane == 34) val = -0.5f;
    else if (lane == 35) val = 0.5f * (last + MARGIN);
    if (lane < 48) qs[lane] = (lane < 36) ? f2bf(val) : (unsigned short)0;
    __syncthreads();
    // pack A-frags: chunk (s,half) = q-hat shorts [s*16+half*8 .. +8]
    // dest lane-id in a filter wave = half*32 + mrow, query row = qt*32+mrow
    if (lane < 6) {
        int s = lane >> 1, half = lane & 1;
        int qt = b >> 5, mrow = b & 31;
        v8s frag = *(const v8s*)&qs[s * 16 + half * 8];
        afrag[(qt * 3 + s) * 64 + half * 32 + mrow] = frag;
    }
}

// --- kernel 1: MFMA bf16 filter; R3 structure + REGISTER-PINNED A-frags -----
// R7/R8 counter evidence (fused kernel, VGPR=104 < the 96 needed for A alone,
// no spill-store traffic): the compiler REMATERIALIZES the hoisted A-frags,
// re-loading afrag[] from memory inside every qt iteration -> 3 dependent
// L1/L2 loads + vmcnt wait before every MFMA triple. That silently undid every
// hoist since R1 and explains the flat 34-40us plateau. Fix: an empty asm
// with "+v" constraint makes each A value opaque -> cannot be rematerialized,
// must stay register-resident (~180 VGPR < 256 cap at 2 blocks/CU, no spill).
__global__ __launch_bounds__(256, 2) void k_filter(const float* __restrict__ msa,
                                                   const v8s* __restrict__ afrag,
                                                   int* __restrict__ cursor,
                                                   unsigned* __restrict__ pbuf,
                                                   int* __restrict__ posq) {
    __shared__ int lcount[NB];                               // 1024 B
    __shared__ int lcand[NB * LCAP];                         // 8192 B
    __shared__ int gbase;
    const int g = blockIdx.x, t = threadIdx.x;
    const int w = t >> 6, lane = t & 63;
    const int mrow = lane & 31, half = lane >> 5;
    // hoist ALL A-fragments (lane-only dependence) — then PIN them in VGPRs
    v8s A[8][3];
#pragma unroll
    for (int qt = 0; qt < 8; ++qt)
#pragma unroll
        for (int s = 0; s < 3; ++s)
            A[qt][s] = afrag[(qt * 3 + s) * 64 + lane];
#pragma unroll
    for (int qt = 0; qt < 8; ++qt)
#pragma unroll
        for (int s = 0; s < 3; ++s)
            asm volatile("" : "+v"(A[qt][s]));  // opaque: no remat, stays in regs
    lcount[t] = 0;
    __syncthreads();
    const v16f zacc = (v16f)0.0f;               // persistent zero C-input
    const int gw = g * 4 + w;                   // global wave id
    const int step = FBLK * 4;

    // process one chunk from a register buffer (inlined; all indices static)
    auto process = [&](const float2* c, int wc) {
        const int p0 = wc * 32 + mrow;
        // per-lane partial fp32 norm; lane pair (half0,half1) shares the row
        float n0 = 0.f, n1 = 0.f;
        n0 = fmaf(c[0].x, c[0].x, n0); n1 = fmaf(c[0].y, c[0].y, n1);
        n0 = fmaf(c[1].x, c[1].x, n0); n1 = fmaf(c[1].y, c[1].y, n1);
        n0 = fmaf(c[2].x, c[2].x, n0); n1 = fmaf(c[2].y, c[2].y, n1);
        n0 = fmaf(c[3].x, c[3].x, n0); n1 = fmaf(c[3].y, c[3].y, n1);
        n0 = fmaf(c[4].x, c[4].x, n0); n1 = fmaf(c[4].y, c[4].y, n1);
        n0 = fmaf(c[5].x, c[5].x, n0); n1 = fmaf(c[5].y, c[5].y, n1);
        n0 = fmaf(c[6].x, c[6].x, n0); n1 = fmaf(c[6].y, c[6].y, n1);
        n0 = fmaf(c[7].x, c[7].x, n0); n1 = fmaf(c[7].y, c[7].y, n1);
        float part = n0 + n1;
        part = fmaf(c[8].x, c[8].x * 0.5f, part);   // half of dims 32/33 per lane
        part = fmaf(c[8].y, c[8].y * 0.5f, part);
        float nrm = part + __shfl_xor(part, 32);
        float thr = 0.5f * nrm;                 // hit iff acc >= thr
        // B-frags: shufflevector-of-pk2 (proven no-spill) + literal-index B2
        v4s b0lo = __builtin_shufflevector(pk2(c[0]), pk2(c[1]), 0, 1, 2, 3);
        v4s b0hi = __builtin_shufflevector(pk2(c[2]), pk2(c[3]), 0, 1, 2, 3);
        v8s B0 = __builtin_shufflevector(b0lo, b0hi, 0, 1, 2, 3, 4, 5, 6, 7);
        v4s b1lo = __builtin_shufflevector(pk2(c[4]), pk2(c[5]), 0, 1, 2, 3);
        v4s b1hi = __builtin_shufflevector(pk2(c[6]), pk2(c[7]), 0, 1, 2, 3);
        v8s B1 = __builtin_shufflevector(b1lo, b1hi, 0, 1, 2, 3, 4, 5, 6, 7);
        v8s B2 = (v8s)(short)0;
        if (half == 0) {
            v2s m33 = pk2(c[8]);
            B2[0] = m33[0];                     // m32 (k=32)
            B2[1] = m33[1];                     // m33 (k=33)
            B2[3] = (short)0x3F80;              // k=35: 1.0 pairs q's tau-term
        }                                       // k=34 stays 0 (pairs q's -0.5)
#pragma unroll
        for (int qt = 0; qt < 8; ++qt) {
            v16f acc = __builtin_amdgcn_mfma_f32_32x32x16_bf16(A[qt][0], B0, zacc, 0, 0, 0);
            acc = __builtin_amdgcn_mfma_f32_32x32x16_bf16(A[qt][1], B1, acc, 0, 0, 0);
            acc = __builtin_amdgcn_mfma_f32_32x32x16_bf16(A[qt][2], B2, acc, 0, 0, 0);
            // 3-ary max tree (fuses to v_max3_f32): skip mask scan on no hit
            float m0 = fmaxf(fmaxf(acc[0], acc[1]), acc[2]);
            float m1 = fmaxf(fmaxf(acc[3], acc[4]), acc[5]);
            float m2 = fmaxf(fmaxf(acc[6], acc[7]), acc[8]);
            float m3 = fmaxf(fmaxf(acc[9], acc[10]), acc[11]);
            float m4 = fmaxf(fmaxf(acc[12], acc[13]), acc[14]);
            float mx = fmaxf(fmaxf(fmaxf(m0, m1), m2),
                             fmaxf(fmaxf(m3, m4), acc[15]));
            if (mx >= thr) {
                unsigned hm = 0;
#pragma unroll
                for (int r = 0; r < 16; ++r) hm |= (acc[r] >= thr) ? (1u << r) : 0u;
                while (hm) {                    // rare per lane
                    int r = __builtin_ctz(hm);
                    hm &= hm - 1;
                    int qq = qt * 32 + (r & 3) + 8 * (r >> 2) + 4 * half;
                    int slot = atomicAdd(&lcount[qq], 1);
                    if (slot < LCAP) lcand[qq * LCAP + slot] = p0;
                    else {                      // SAFE overflow: side region
                        int dg = atomicAdd(cursor + 1, 1);
                        if (dg < OCAP) pbuf[PMAIN + dg] = ((unsigned)qq << 19) | (unsigned)p0;
                    }
                }
            }
        }
    };

    float2 bufA[9], bufB[9];
    int wc = gw;                                 // gw < 2048 <= NWCH always
    load9(bufA, msa + (size_t)(wc * 32 + mrow) * 34, half);  // prologue
#pragma unroll 1
    for (;;) {
        const int w1 = wc + step;
        {   // prefetch next into B; sched_barrier pins issue BEFORE compute
            const int pn = (w1 < NWCH) ? w1 : gw;
            load9(bufB, msa + (size_t)(pn * 32 + mrow) * 34, half);
        }
        __builtin_amdgcn_sched_barrier(0);
        process(bufA, wc);
        wc = w1;
        if (wc >= NWCH) break;
        const int w2 = wc + step;
        {   // prefetch next into A
            const int pn = (w2 < NWCH) ? w2 : gw;
            load9(bufA, msa + (size_t)(pn * 32 + mrow) * 34, half);
        }
        __builtin_amdgcn_sched_barrier(0);
        process(bufB, wc);
        wc = w2;
        if (wc >= NWCH) break;
    }
    __syncthreads();
    // flush: prefix-scan -> ONE cursor atomic -> compacted writes + pos table
    int n = lcount[t];
    if (n > LCAP) n = LCAP;
    lcount[t] = n;
    __syncthreads();
    for (int off = 1; off < 256; off <<= 1) {   // Hillis-Steele inclusive scan
        int v = (t >= off) ? lcount[t - off] : 0;
        __syncthreads();
        lcount[t] += v;
        __syncthreads();
    }
    int base_l = lcount[t] - n;
    if (t == 255) gbase = atomicAdd(cursor, lcount[255]);
    __syncthreads();
    int start = gbase + base_l;
    if (start >= PMAIN) { start = 0; n = 0; }
    else if (start + n > PMAIN) n = PMAIN - start;
    posq[g * NB + t] = start | (n << 20);       // coalesced, no atomic
    for (int i = 0; i < n; ++i)
        pbuf[start + i] = (unsigned)lcand[t * LCAP + i];
}

// --- kernel 2: gather my segments, exact fp32 rescore, top-10, softmax ------
__global__ __launch_bounds__(256) void k_final(const float* __restrict__ obs,
                                               const float* __restrict__ act,
                                               const float* __restrict__ msa,
                                               const unsigned* __restrict__ pbuf,
                                               const int* __restrict__ posq,
                                               const int* __restrict__ cursor,
                                               const float* __restrict__ memQ,
                                               float* __restrict__ out) {
    __shared__ float ls[CAP];
    __shared__ int   li[CAP];
    __shared__ int   sc[NB];
    __shared__ int   lcnt;
    __shared__ float rs[4];
    __shared__ int   ri[4];
    __shared__ float sel_s[TOPK];
    __shared__ int   sel_i[TOPK];
    const int b = blockIdx.x, t = threadIdx.x;
    const int lane = t & 63, wid = t >> 6;
    // gather my posq segments (FBLK = NSEG*256 -> NSEG fixed slots)
    int nk[NSEG], pk6[NSEG], tot = 0;
#pragma unroll
    for (int k = 0; k < NSEG; ++k) {
        int packed = posq[(size_t)(t + 256 * k) * NB + b];
        nk[k] = (packed >> 20) & 0xF;
        pk6[k] = packed & 0xFFFFF;
        tot += nk[k];
    }
    sc[t] = tot;
    __syncthreads();
    for (int off = 1; off < 256; off <<= 1) {   // prefix scan (no atomics)
        int v = (t >= off) ? sc[t - off] : 0;
        __syncthreads();
        sc[t] += v;
        __syncthreads();
    }
    int myoff = sc[t] - tot;
    if (t == 0) lcnt = (sc[255] > CAP) ? CAP : sc[255];
    __syncthreads();
#pragma unroll
    for (int k = 0; k < NSEG; ++k)
        for (int i = 0; i < nk[k]; ++i) {
            if (myoff < CAP) li[myoff] = (int)pbuf[pk6[k] + i];
            ++myoff;
        }
    // overflow region (normally empty)
    int novf = cursor[1];
    if (novf > OCAP) novf = OCAP;
    for (int j = t; j < novf; j += 256) {
        unsigned pr = pbuf[PMAIN + j];
        if ((int)(pr >> 19) == b) {
            int s = atomicAdd(&lcnt, 1);
            if (s < CAP) li[s] = (int)(pr & 0x7FFFFu);
        }
    }
    __syncthreads();
    int cnt = lcnt;
    if (cnt > CAP) cnt = CAP;
    float q[34];
    load_q(obs, act, b, q);
    for (int j = t; j < cnt; j += 256) {        // exact fp32 re-scores
        const float* row = msa + (size_t)li[j] * 34;
        ls[j] = fmaf(-2.f, dot34(row, q), norm34(row));
    }
    __syncthreads();
    for (int k = 0; k < TOPK; ++k) {
        float bs = __builtin_inff();
        int   bi = 0x7fffffff;
        for (int j = t; j < cnt; j += 256) {
            float s = ls[j]; int i = li[j];
            if (s < bs || (s == bs && i < bi)) { bs = s; bi = i; }
        }
        for (int off = 32; off; off >>= 1) {
            float s2 = __shfl_down(bs, off);
            int   i2 = __shfl_down(bi, off);
            if (s2 < bs || (s2 == bs && i2 < bi)) { bs = s2; bi = i2; }
        }
        if (lane == 0) { rs[wid] = bs; ri[wid] = bi; }
        __syncthreads();
        if (t == 0) {
            float fs = rs[0]; int fi = ri[0];
#pragma unroll
            for (int ww = 1; ww < 4; ++ww) {
                if (rs[ww] < fs || (rs[ww] == fs && ri[ww] < fi)) { fs = rs[ww]; fi = ri[ww]; }
            }
            sel_s[k] = fs; sel_i[k] = fi;
        }
        __syncthreads();
        const int win = sel_i[k];
        for (int j = t; j < cnt; j += 256) {
            if (li[j] == win) ls[j] = __builtin_inff();
        }
        __syncthreads();
    }
    if (t == 0) {
        float m = sel_s[TOPK - 1];
        float wsum = 0.f, acc = 0.f;
#pragma unroll
        for (int k = 0; k < TOPK; ++k) {
            if (sel_i[k] == 0x7fffffff) continue;
            float w2 = expf(sel_s[k] - m);
            wsum += w2;
            acc = fmaf(w2, memQ[sel_i[k]], acc);
        }
        out[b] = acc / wsum;
    }
}

extern "C" void kernel_launch(void* const* d_in, const int* in_sizes, int n_in,
                              void* d_out, int out_size, void* d_ws, size_t ws_size,
                              hipStream_t stream) {
    const float* obs = (const float*)d_in[0];   // [256,32]
    const float* act = (const float*)d_in[1];   // [256,2]
    const float* msa = (const float*)d_in[2];   // [500000,34]
    const float* mq  = (const float*)d_in[3];   // [500000,1]
    float* out = (float*)d_out;                 // [256]

    char* ws = (char*)d_ws;
    int*      cursor = (int*)ws;                            // 8 B
    v8s*      afrag  = (v8s*)(ws + 256);                    // 24576 B
    float*    minima = (float*)(ws + 32768);                // 1 MB (256 x 1024)
    int*      posq   = (int*)(ws + 32768 + 1048576);        // 512 KB used
    unsigned* pbuf   = (unsigned*)(ws + 32768 + 1048576 + 1572864); // 1703936 B
    // total ws use ~4.3 MB

    k_sample<<<SBLK, 256, 0, stream>>>(obs, act, msa, minima);
    k_tau   <<<NB, 64, 0, stream>>>(minima, obs, act, afrag, cursor);
    k_filter<<<FBLK, 256, 0, stream>>>(msa, afrag, cursor, pbuf, posq);
    k_final <<<NB, 256, 0, stream>>>(obs, act, msa, pbuf, posq, cursor, mq, out);
}

// Round 10
// 169.030 us; speedup vs baseline: 1.8184x; 1.0053x over previous
//
#include <hip/hip_runtime.h>
#include <hip/hip_bf16.h>
#include <math.h>

#define NPTS   500000
#define NB     256
#define TOPK   10
#define CAP    2048        // per-query candidate cap in k_final
#define SBLK   1024        // sample slices
#define SPER   16          // points per slice -> 16384-pt sample
#define MARGIN 2.0f        // bf16 dot err <~0.5; 4x headroom
#define NWCH   15625       // 500000 / 32: wave-chunks of 32 points (exact!)
#define FBLK   512         // k_filter grid: 2 blocks/CU resident, ONE round
#define NSEG   2           // FBLK / 256: posq segments read by k_final
#define LCAP   8           // per-(block,query) local cap; overflow safe-path
#define OVFC   2048        // per-block LDS overflow list (expected ~0.2 used)
#define PMAIN  393216      // main pair region (dwords) < 2^20
#define OCAP   32768       // overflow pair region (dwords)

typedef short v2s  __attribute__((ext_vector_type(2)));
typedef short v4s  __attribute__((ext_vector_type(4)));
typedef short v8s  __attribute__((ext_vector_type(8)));
typedef float v16f __attribute__((ext_vector_type(16)));

__device__ __forceinline__ unsigned short f2bf(float f) {   // RNE
    unsigned u = __float_as_uint(f);
    unsigned r = u + 0x7FFFu + ((u >> 16) & 1u);
    return (unsigned short)(r >> 16);
}
// packed f32x2 -> bf16x2 (hw cvt, RNE; lo short = f.x). memcpy-pun: legal & proven.
__device__ __forceinline__ v2s pk2(float2 f) {
    __hip_bfloat162 h = __float22bfloat162_rn(f);
    v2s r;
    __builtin_memcpy(&r, &h, 4);
    return r;
}

// --- exact fp32 pieces: bitwise-identical order in k_sample and k_final -----
__device__ __forceinline__ float norm34(const float* __restrict__ r) {
    float a0 = 0.f, a1 = 0.f, a2 = 0.f, a3 = 0.f;
#pragma unroll
    for (int d = 0; d < 32; d += 4) {
        a0 = fmaf(r[d + 0], r[d + 0], a0);
        a1 = fmaf(r[d + 1], r[d + 1], a1);
        a2 = fmaf(r[d + 2], r[d + 2], a2);
        a3 = fmaf(r[d + 3], r[d + 3], a3);
    }
    a0 = fmaf(r[32], r[32], a0);
    a1 = fmaf(r[33], r[33], a1);
    return (a0 + a1) + (a2 + a3);
}
__device__ __forceinline__ float dot34(const float* __restrict__ r, const float* q) {
    float a0 = 0.f, a1 = 0.f, a2 = 0.f, a3 = 0.f;
#pragma unroll
    for (int d = 0; d < 32; d += 4) {
        a0 = fmaf(r[d + 0], q[d + 0], a0);
        a1 = fmaf(r[d + 1], q[d + 1], a1);
        a2 = fmaf(r[d + 2], q[d + 2], a2);
        a3 = fmaf(r[d + 3], q[d + 3], a3);
    }
    a0 = fmaf(r[32], q[32], a0);
    a1 = fmaf(r[33], q[33], a1);
    return (a0 + a1) + (a2 + a3);
}
// float4 LDS variant, IDENTICAL fma order -> bitwise-equal s
__device__ __forceinline__ float dot34_v4(const float4* __restrict__ r4, const float* q) {
    float a0 = 0.f, a1 = 0.f, a2 = 0.f, a3 = 0.f;
#pragma unroll
    for (int dp = 0; dp < 8; ++dp) {
        float4 v = r4[dp];
        a0 = fmaf(v.x, q[4 * dp + 0], a0);
        a1 = fmaf(v.y, q[4 * dp + 1], a1);
        a2 = fmaf(v.z, q[4 * dp + 2], a2);
        a3 = fmaf(v.w, q[4 * dp + 3], a3);
    }
    float2 t = *(const float2*)(r4 + 8);
    a0 = fmaf(t.x, q[32], a0);
    a1 = fmaf(t.y, q[33], a1);
    return (a0 + a1) + (a2 + a3);
}
__device__ __forceinline__ void load_q(const float* __restrict__ obs,
                                       const float* __restrict__ act, int b, float* q) {
#pragma unroll
    for (int d = 0; d < 32; ++d) q[d] = obs[b * 32 + d];
    q[32] = act[b * 2 + 0];
    q[33] = act[b * 2 + 1];
}
// this lane's 9 float2 pieces of one msa row (half-split K dims + dims 32/33)
__device__ __forceinline__ void load9(float2* __restrict__ e,
                                      const float* __restrict__ rp, int half) {
    e[0] = *(const float2*)(rp + half * 8 + 0);
    e[1] = *(const float2*)(rp + half * 8 + 2);
    e[2] = *(const float2*)(rp + half * 8 + 4);
    e[3] = *(const float2*)(rp + half * 8 + 6);
    e[4] = *(const float2*)(rp + 16 + half * 8 + 0);
    e[5] = *(const float2*)(rp + 16 + half * 8 + 2);
    e[6] = *(const float2*)(rp + 16 + half * 8 + 4);
    e[7] = *(const float2*)(rp + 16 + half * 8 + 6);
    e[8] = *(const float2*)(rp + 32);
}

// --- kernel 0a: per-(query, 16-pt slice) min of s; minima transposed --------
__global__ __launch_bounds__(256, 4) void k_sample(const float* __restrict__ obs,
                                                   const float* __restrict__ act,
                                                   const float* __restrict__ msa,
                                                   float* __restrict__ minima) {
    __shared__ __align__(16) float sm[SPER * 36];
    __shared__ float smn[SPER];
    const int g = blockIdx.x, t = threadIdx.x;
    const int base = g * SPER;
    for (int i = t; i < SPER * 34; i += 256) {
        int row = i / 34, d = i - row * 34;
        sm[row * 36 + d] = msa[(size_t)base * 34 + i];
    }
    __syncthreads();
    if (t < SPER) smn[t] = norm34(&sm[t * 36]);
    __syncthreads();
    float q[34];
    load_q(obs, act, t, q);
    float best = __builtin_inff();
#pragma unroll
    for (int j = 0; j < SPER; ++j) {
        float s = fmaf(-2.f, dot34_v4((const float4*)&sm[j * 36], q), smn[j]);
        best = fminf(best, s);
    }
    minima[(size_t)t * SBLK + g] = best;          // transposed: k_tau coalesced
}

// --- kernel 0b: tau = 10th-smallest slice-min; pack A-frags; zero cursors ---
__global__ __launch_bounds__(64) void k_tau(const float* __restrict__ minima,
                                            const float* __restrict__ obs,
                                            const float* __restrict__ act,
                                            v8s* __restrict__ afrag,
                                            int* __restrict__ cursor) {
    __shared__ __align__(16) unsigned short qs[48];
    const int b = blockIdx.x, lane = threadIdx.x;
    if (b == 0 && lane == 0) { cursor[0] = 0; cursor[1] = 0; }
    float v[16];
#pragma unroll
    for (int k = 0; k < 16; ++k) v[k] = minima[(size_t)b * SBLK + lane + 64 * k];
    float last = 0.f;
    for (int r = 0; r < TOPK; ++r) {
        float lm = v[0]; int la = 0;
#pragma unroll
        for (int k = 1; k < 16; ++k) { if (v[k] < lm) { lm = v[k]; la = k; } }
        float wm = lm;
        for (int off = 32; off; off >>= 1) wm = fminf(wm, __shfl_xor(wm, off));
        unsigned long long msk = __ballot(lm == wm);
        int first = (int)__builtin_ctzll(msk);
        if (lane == first) {
#pragma unroll
            for (int k = 0; k < 16; ++k) { if (k == la) v[k] = __builtin_inff(); }
        }
        last = wm;   // wave-uniform
    }
    // q-hat = [q(34), -0.5, (tau+MARGIN)/2, 0..0] as bf16 in LDS
    float val = 0.f;
    if (lane < 32)       val = obs[b * 32 + lane];
    else if (lane < 34)  val = act[b * 2 + (lane - 32)];
    else if (lane == 34) val = -0.5f;
    else if (lane == 35) val = 0.5f * (last + MARGIN);
    if (lane < 48) qs[lane] = (lane < 36) ? f2bf(val) : (unsigned short)0;
    __syncthreads();
    // pack A-frags: chunk (s,half) = q-hat shorts [s*16+half*8 .. +8]
    // dest lane-id in a filter wave = half*32 + mrow, query row = qt*32+mrow
    if (lane < 6) {
        int s = lane >> 1, half = lane & 1;
        int qt = b >> 5, mrow = b & 31;
        v8s frag = *(const v8s*)&qs[s * 16 + half * 8];
        afrag[(qt * 3 + s) * 64 + half * 32 + mrow] = frag;
    }
}

// --- kernel 1: MFMA bf16 filter; VMEM-STORE-FREE chunk loop -----------------
// Theory (R0-R9 synthesis): the hit path's conditional global atomic+store
// made the number of outstanding vmem ops dynamically unknown -> before each
// prefetched-buffer consume the compiler MUST emit s_waitcnt vmcnt(0),
// draining the just-issued prefetch. Every pipeline since R2 (ping-pong,
// sched_barrier, LDS staging) was silently serialized to full-latency-per-
// chunk by those two instructions — the structure-invariant 34-37us plateau.
// Fix: overflow hits go to a per-block LDS list (2048 entries vs ~0.2
// expected; same capacity-capped semantics the global OCAP region already
// had), flushed AFTER the loop. Loop's only vmem ops = the 18 pipelined
// loads -> counted vmcnt(9) -> the double-buffer finally overlaps.
__global__ __launch_bounds__(256, 2) void k_filter(const float* __restrict__ msa,
                                                   const v8s* __restrict__ afrag,
                                                   int* __restrict__ cursor,
                                                   unsigned* __restrict__ pbuf,
                                                   int* __restrict__ posq) {
    __shared__ int lcount[NB];                               // 1024 B
    __shared__ int lcand[NB * LCAP];                         // 8192 B
    __shared__ unsigned ovf[OVFC];                           // 8192 B
    __shared__ int ovfn;
    __shared__ int gbase;
    const int g = blockIdx.x, t = threadIdx.x;
    const int w = t >> 6, lane = t & 63;
    const int mrow = lane & 31, half = lane >> 5;
    // hoist ALL A-fragments (lane-only dependence) — then PIN them in VGPRs
    v8s A[8][3];
#pragma unroll
    for (int qt = 0; qt < 8; ++qt)
#pragma unroll
        for (int s = 0; s < 3; ++s)
            A[qt][s] = afrag[(qt * 3 + s) * 64 + lane];
#pragma unroll
    for (int qt = 0; qt < 8; ++qt)
#pragma unroll
        for (int s = 0; s < 3; ++s)
            asm volatile("" : "+v"(A[qt][s]));  // opaque: no remat, stays in regs
    lcount[t] = 0;
    if (t == 0) ovfn = 0;
    __syncthreads();
    const v16f zacc = (v16f)0.0f;               // persistent zero C-input
    const int gw = g * 4 + w;                   // global wave id
    const int step = FBLK * 4;

    // process one chunk from a register buffer (inlined; all indices static).
    // NO global-memory ops anywhere in here -> vmcnt stays countable.
    auto process = [&](const float2* c, int wc) {
        const int p0 = wc * 32 + mrow;
        // per-lane partial fp32 norm; lane pair (half0,half1) shares the row
        float n0 = 0.f, n1 = 0.f;
        n0 = fmaf(c[0].x, c[0].x, n0); n1 = fmaf(c[0].y, c[0].y, n1);
        n0 = fmaf(c[1].x, c[1].x, n0); n1 = fmaf(c[1].y, c[1].y, n1);
        n0 = fmaf(c[2].x, c[2].x, n0); n1 = fmaf(c[2].y, c[2].y, n1);
        n0 = fmaf(c[3].x, c[3].x, n0); n1 = fmaf(c[3].y, c[3].y, n1);
        n0 = fmaf(c[4].x, c[4].x, n0); n1 = fmaf(c[4].y, c[4].y, n1);
        n0 = fmaf(c[5].x, c[5].x, n0); n1 = fmaf(c[5].y, c[5].y, n1);
        n0 = fmaf(c[6].x, c[6].x, n0); n1 = fmaf(c[6].y, c[6].y, n1);
        n0 = fmaf(c[7].x, c[7].x, n0); n1 = fmaf(c[7].y, c[7].y, n1);
        float part = n0 + n1;
        part = fmaf(c[8].x, c[8].x * 0.5f, part);   // half of dims 32/33 per lane
        part = fmaf(c[8].y, c[8].y * 0.5f, part);
        float nrm = part + __shfl_xor(part, 32);
        float thr = 0.5f * nrm;                 // hit iff acc >= thr
        // B-frags: shufflevector-of-pk2 (proven no-spill) + literal-index B2
        v4s b0lo = __builtin_shufflevector(pk2(c[0]), pk2(c[1]), 0, 1, 2, 3);
        v4s b0hi = __builtin_shufflevector(pk2(c[2]), pk2(c[3]), 0, 1, 2, 3);
        v8s B0 = __builtin_shufflevector(b0lo, b0hi, 0, 1, 2, 3, 4, 5, 6, 7);
        v4s b1lo = __builtin_shufflevector(pk2(c[4]), pk2(c[5]), 0, 1, 2, 3);
        v4s b1hi = __builtin_shufflevector(pk2(c[6]), pk2(c[7]), 0, 1, 2, 3);
        v8s B1 = __builtin_shufflevector(b1lo, b1hi, 0, 1, 2, 3, 4, 5, 6, 7);
        v8s B2 = (v8s)(short)0;
        if (half == 0) {
            v2s m33 = pk2(c[8]);
            B2[0] = m33[0];                     // m32 (k=32)
            B2[1] = m33[1];                     // m33 (k=33)
            B2[3] = (short)0x3F80;              // k=35: 1.0 pairs q's tau-term
        }                                       // k=34 stays 0 (pairs q's -0.5)
#pragma unroll
        for (int qt = 0; qt < 8; ++qt) {
            v16f acc = __builtin_amdgcn_mfma_f32_32x32x16_bf16(A[qt][0], B0, zacc, 0, 0, 0);
            acc = __builtin_amdgcn_mfma_f32_32x32x16_bf16(A[qt][1], B1, acc, 0, 0, 0);
            acc = __builtin_amdgcn_mfma_f32_32x32x16_bf16(A[qt][2], B2, acc, 0, 0, 0);
            // 3-ary max tree (fuses to v_max3_f32): skip mask scan on no hit
            float m0 = fmaxf(fmaxf(acc[0], acc[1]), acc[2]);
            float m1 = fmaxf(fmaxf(acc[3], acc[4]), acc[5]);
            float m2 = fmaxf(fmaxf(acc[6], acc[7]), acc[8]);
            float m3 = fmaxf(fmaxf(acc[9], acc[10]), acc[11]);
            float m4 = fmaxf(fmaxf(acc[12], acc[13]), acc[14]);
            float mx = fmaxf(fmaxf(fmaxf(m0, m1), m2),
                             fmaxf(fmaxf(m3, m4), acc[15]));
            if (mx >= thr) {
                unsigned hm = 0;
#pragma unroll
                for (int r = 0; r < 16; ++r) hm |= (acc[r] >= thr) ? (1u << r) : 0u;
                while (hm) {                    // rare per lane; LDS-ONLY path
                    int r = __builtin_ctz(hm);
                    hm &= hm - 1;
                    int qq = qt * 32 + (r & 3) + 8 * (r >> 2) + 4 * half;
                    int slot = atomicAdd(&lcount[qq], 1);
                    if (slot < LCAP) lcand[qq * LCAP + slot] = p0;
                    else {                      // overflow -> per-block LDS list
                        int dg = atomicAdd(&ovfn, 1);
                        if (dg < OVFC) ovf[dg] = ((unsigned)qq << 19) | (unsigned)p0;
                    }
                }
            }
        }
    };

    float2 bufA[9], bufB[9];
    int wc = gw;                                 // gw < 2048 <= NWCH always
    load9(bufA, msa + (size_t)(wc * 32 + mrow) * 34, half);  // prologue
#pragma unroll 1
    for (;;) {
        const int w1 = wc + step;
        {   // prefetch next into B; sched_barrier pins issue BEFORE compute
            const int pn = (w1 < NWCH) ? w1 : gw;
            load9(bufB, msa + (size_t)(pn * 32 + mrow) * 34, half);
        }
        __builtin_amdgcn_sched_barrier(0);
        process(bufA, wc);
        wc = w1;
        if (wc >= NWCH) break;
        const int w2 = wc + step;
        {   // prefetch next into A
            const int pn = (w2 < NWCH) ? w2 : gw;
            load9(bufA, msa + (size_t)(pn * 32 + mrow) * 34, half);
        }
        __builtin_amdgcn_sched_barrier(0);
        process(bufB, wc);
        wc = w2;
        if (wc >= NWCH) break;
    }
    __syncthreads();
    // flush LDS overflow list to the global overflow region (usually empty)
    {
        int no = ovfn;
        if (no > OVFC) no = OVFC;
        for (int i = t; i < no; i += 256) {
            int dg = atomicAdd(cursor + 1, 1);
            if (dg < OCAP) pbuf[PMAIN + dg] = ovf[i];
        }
    }
    // flush: prefix-scan -> ONE cursor atomic -> compacted writes + pos table
    int n = lcount[t];
    if (n > LCAP) n = LCAP;
    lcount[t] = n;
    __syncthreads();
    for (int off = 1; off < 256; off <<= 1) {   // Hillis-Steele inclusive scan
        int v = (t >= off) ? lcount[t - off] : 0;
        __syncthreads();
        lcount[t] += v;
        __syncthreads();
    }
    int base_l = lcount[t] - n;
    if (t == 255) gbase = atomicAdd(cursor, lcount[255]);
    __syncthreads();
    int start = gbase + base_l;
    if (start >= PMAIN) { start = 0; n = 0; }
    else if (start + n > PMAIN) n = PMAIN - start;
    posq[g * NB + t] = start | (n << 20);       // coalesced, no atomic
    for (int i = 0; i < n; ++i)
        pbuf[start + i] = (unsigned)lcand[t * LCAP + i];
}

// --- kernel 2: gather my segments, exact fp32 rescore, top-10, softmax ------
__global__ __launch_bounds__(256) void k_final(const float* __restrict__ obs,
                                               const float* __restrict__ act,
                                               const float* __restrict__ msa,
                                               const unsigned* __restrict__ pbuf,
                                               const int* __restrict__ posq,
                                               const int* __restrict__ cursor,
                                               const float* __restrict__ memQ,
                                               float* __restrict__ out) {
    __shared__ float ls[CAP];
    __shared__ int   li[CAP];
    __shared__ int   sc[NB];
    __shared__ int   lcnt;
    __shared__ float rs[4];
    __shared__ int   ri[4];
    __shared__ float sel_s[TOPK];
    __shared__ int   sel_i[TOPK];
    const int b = blockIdx.x, t = threadIdx.x;
    const int lane = t & 63, wid = t >> 6;
    // gather my posq segments (FBLK = NSEG*256 -> NSEG fixed slots)
    int nk[NSEG], pk6[NSEG], tot = 0;
#pragma unroll
    for (int k = 0; k < NSEG; ++k) {
        int packed = posq[(size_t)(t + 256 * k) * NB + b];
        nk[k] = (packed >> 20) & 0xF;
        pk6[k] = packed & 0xFFFFF;
        tot += nk[k];
    }
    sc[t] = tot;
    __syncthreads();
    for (int off = 1; off < 256; off <<= 1) {   // prefix scan (no atomics)
        int v = (t >= off) ? sc[t - off] : 0;
        __syncthreads();
        sc[t] += v;
        __syncthreads();
    }
    int myoff = sc[t] - tot;
    if (t == 0) lcnt = (sc[255] > CAP) ? CAP : sc[255];
    __syncthreads();
#pragma unroll
    for (int k = 0; k < NSEG; ++k)
        for (int i = 0; i < nk[k]; ++i) {
            if (myoff < CAP) li[myoff] = (int)pbuf[pk6[k] + i];
            ++myoff;
        }
    // overflow region (normally empty)
    int novf = cursor[1];
    if (novf > OCAP) novf = OCAP;
    for (int j = t; j < novf; j += 256) {
        unsigned pr = pbuf[PMAIN + j];
        if ((int)(pr >> 19) == b) {
            int s = atomicAdd(&lcnt, 1);
            if (s < CAP) li[s] = (int)(pr & 0x7FFFFu);
        }
    }
    __syncthreads();
    int cnt = lcnt;
    if (cnt > CAP) cnt = CAP;
    float q[34];
    load_q(obs, act, b, q);
    for (int j = t; j < cnt; j += 256) {        // exact fp32 re-scores
        const float* row = msa + (size_t)li[j] * 34;
        ls[j] = fmaf(-2.f, dot34(row, q), norm34(row));
    }
    __syncthreads();
    for (int k = 0; k < TOPK; ++k) {
        float bs = __builtin_inff();
        int   bi = 0x7fffffff;
        for (int j = t; j < cnt; j += 256) {
            float s = ls[j]; int i = li[j];
            if (s < bs || (s == bs && i < bi)) { bs = s; bi = i; }
        }
        for (int off = 32; off; off >>= 1) {
            float s2 = __shfl_down(bs, off);
            int   i2 = __shfl_down(bi, off);
            if (s2 < bs || (s2 == bs && i2 < bi)) { bs = s2; bi = i2; }
        }
        if (lane == 0) { rs[wid] = bs; ri[wid] = bi; }
        __syncthreads();
        if (t == 0) {
            float fs = rs[0]; int fi = ri[0];
#pragma unroll
            for (int ww = 1; ww < 4; ++ww) {
                if (rs[ww] < fs || (rs[ww] == fs && ri[ww] < fi)) { fs = rs[ww]; fi = ri[ww]; }
            }
            sel_s[k] = fs; sel_i[k] = fi;
        }
        __syncthreads();
        const int win = sel_i[k];
        for (int j = t; j < cnt; j += 256) {
            if (li[j] == win) ls[j] = __builtin_inff();
        }
        __syncthreads();
    }
    if (t == 0) {
        float m = sel_s[TOPK - 1];
        float wsum = 0.f, acc = 0.f;
#pragma unroll
        for (int k = 0; k < TOPK; ++k) {
            if (sel_i[k] == 0x7fffffff) continue;
            float w2 = expf(sel_s[k] - m);
            wsum += w2;
            acc = fmaf(w2, memQ[sel_i[k]], acc);
        }
        out[b] = acc / wsum;
    }
}

extern "C" void kernel_launch(void* const* d_in, const int* in_sizes, int n_in,
                              void* d_out, int out_size, void* d_ws, size_t ws_size,
                              hipStream_t stream) {
    const float* obs = (const float*)d_in[0];   // [256,32]
    const float* act = (const float*)d_in[1];   // [256,2]
    const float* msa = (const float*)d_in[2];   // [500000,34]
    const float* mq  = (const float*)d_in[3];   // [500000,1]
    float* out = (float*)d_out;                 // [256]

    char* ws = (char*)d_ws;
    int*      cursor = (int*)ws;                            // 8 B
    v8s*      afrag  = (v8s*)(ws + 256);                    // 24576 B
    float*    minima = (float*)(ws + 32768);                // 1 MB (256 x 1024)
    int*      posq   = (int*)(ws + 32768 + 1048576);        // 512 KB used
    unsigned* pbuf   = (unsigned*)(ws + 32768 + 1048576 + 1572864); // 1703936 B
    // total ws use ~4.3 MB

    k_sample<<<SBLK, 256, 0, stream>>>(obs, act, msa, minima);
    k_tau   <<<NB, 64, 0, stream>>>(minima, obs, act, afrag, cursor);
    k_filter<<<FBLK, 256, 0, stream>>>(msa, afrag, cursor, pbuf, posq);
    k_final <<<NB, 256, 0, stream>>>(obs, act, msa, pbuf, posq, cursor, mq, out);
}

// Round 11
// 167.281 us; speedup vs baseline: 1.8374x; 1.0105x over previous
//
#include <hip/hip_runtime.h>
#include <hip/hip_bf16.h>
#include <math.h>

#define NPTS   500000
#define NB     256
#define TOPK   10
#define CAP    2048        // per-query candidate cap in k_final
#define SBLK   1024        // sample slices
#define SPER   16          // points per slice -> 16384-pt sample
#define MARGIN 2.0f        // bf16 dot err <~0.5; 4x headroom
#define NWCH   15625       // 500000 / 32: wave-chunks of 32 points (exact!)
#define FBLK   768         // k_filter grid: 3 blocks/CU resident (TLP +50%)
#define NSEG   3           // FBLK / 256: posq segments read by k_final
#define LCAP   8           // per-(block,query) local cap; overflow safe-path
#define OVFC   2048        // per-block LDS overflow list (expected ~0.2 used)
#define PMAIN  393216      // main pair region (dwords) < 2^20
#define OCAP   32768       // overflow pair region (dwords)

typedef short v2s  __attribute__((ext_vector_type(2)));
typedef short v4s  __attribute__((ext_vector_type(4)));
typedef short v8s  __attribute__((ext_vector_type(8)));
typedef float v16f __attribute__((ext_vector_type(16)));

__device__ __forceinline__ unsigned short f2bf(float f) {   // RNE
    unsigned u = __float_as_uint(f);
    unsigned r = u + 0x7FFFu + ((u >> 16) & 1u);
    return (unsigned short)(r >> 16);
}
// packed f32x2 -> bf16x2 (hw cvt, RNE; lo short = f.x). memcpy-pun: legal & proven.
__device__ __forceinline__ v2s pk2(float2 f) {
    __hip_bfloat162 h = __float22bfloat162_rn(f);
    v2s r;
    __builtin_memcpy(&r, &h, 4);
    return r;
}

// --- exact fp32 pieces: bitwise-identical order in k_sample and k_final -----
__device__ __forceinline__ float norm34(const float* __restrict__ r) {
    float a0 = 0.f, a1 = 0.f, a2 = 0.f, a3 = 0.f;
#pragma unroll
    for (int d = 0; d < 32; d += 4) {
        a0 = fmaf(r[d + 0], r[d + 0], a0);
        a1 = fmaf(r[d + 1], r[d + 1], a1);
        a2 = fmaf(r[d + 2], r[d + 2], a2);
        a3 = fmaf(r[d + 3], r[d + 3], a3);
    }
    a0 = fmaf(r[32], r[32], a0);
    a1 = fmaf(r[33], r[33], a1);
    return (a0 + a1) + (a2 + a3);
}
__device__ __forceinline__ float dot34(const float* __restrict__ r, const float* q) {
    float a0 = 0.f, a1 = 0.f, a2 = 0.f, a3 = 0.f;
#pragma unroll
    for (int d = 0; d < 32; d += 4) {
        a0 = fmaf(r[d + 0], q[d + 0], a0);
        a1 = fmaf(r[d + 1], q[d + 1], a1);
        a2 = fmaf(r[d + 2], q[d + 2], a2);
        a3 = fmaf(r[d + 3], q[d + 3], a3);
    }
    a0 = fmaf(r[32], q[32], a0);
    a1 = fmaf(r[33], q[33], a1);
    return (a0 + a1) + (a2 + a3);
}
// float4 LDS variant, IDENTICAL fma order -> bitwise-equal s
__device__ __forceinline__ float dot34_v4(const float4* __restrict__ r4, const float* q) {
    float a0 = 0.f, a1 = 0.f, a2 = 0.f, a3 = 0.f;
#pragma unroll
    for (int dp = 0; dp < 8; ++dp) {
        float4 v = r4[dp];
        a0 = fmaf(v.x, q[4 * dp + 0], a0);
        a1 = fmaf(v.y, q[4 * dp + 1], a1);
        a2 = fmaf(v.z, q[4 * dp + 2], a2);
        a3 = fmaf(v.w, q[4 * dp + 3], a3);
    }
    float2 t = *(const float2*)(r4 + 8);
    a0 = fmaf(t.x, q[32], a0);
    a1 = fmaf(t.y, q[33], a1);
    return (a0 + a1) + (a2 + a3);
}
__device__ __forceinline__ void load_q(const float* __restrict__ obs,
                                       const float* __restrict__ act, int b, float* q) {
#pragma unroll
    for (int d = 0; d < 32; ++d) q[d] = obs[b * 32 + d];
    q[32] = act[b * 2 + 0];
    q[33] = act[b * 2 + 1];
}
// this lane's 9 float2 pieces of one msa row (half-split K dims + dims 32/33)
__device__ __forceinline__ void load9(float2* __restrict__ e,
                                      const float* __restrict__ rp, int half) {
    e[0] = *(const float2*)(rp + half * 8 + 0);
    e[1] = *(const float2*)(rp + half * 8 + 2);
    e[2] = *(const float2*)(rp + half * 8 + 4);
    e[3] = *(const float2*)(rp + half * 8 + 6);
    e[4] = *(const float2*)(rp + 16 + half * 8 + 0);
    e[5] = *(const float2*)(rp + 16 + half * 8 + 2);
    e[6] = *(const float2*)(rp + 16 + half * 8 + 4);
    e[7] = *(const float2*)(rp + 16 + half * 8 + 6);
    e[8] = *(const float2*)(rp + 32);
}

// --- kernel 0a: per-(query, 16-pt slice) min of s; minima transposed --------
__global__ __launch_bounds__(256, 4) void k_sample(const float* __restrict__ obs,
                                                   const float* __restrict__ act,
                                                   const float* __restrict__ msa,
                                                   float* __restrict__ minima) {
    __shared__ __align__(16) float sm[SPER * 36];
    __shared__ float smn[SPER];
    const int g = blockIdx.x, t = threadIdx.x;
    const int base = g * SPER;
    for (int i = t; i < SPER * 34; i += 256) {
        int row = i / 34, d = i - row * 34;
        sm[row * 36 + d] = msa[(size_t)base * 34 + i];
    }
    __syncthreads();
    if (t < SPER) smn[t] = norm34(&sm[t * 36]);
    __syncthreads();
    float q[34];
    load_q(obs, act, t, q);
    float best = __builtin_inff();
#pragma unroll
    for (int j = 0; j < SPER; ++j) {
        float s = fmaf(-2.f, dot34_v4((const float4*)&sm[j * 36], q), smn[j]);
        best = fminf(best, s);
    }
    minima[(size_t)t * SBLK + g] = best;          // transposed: k_tau coalesced
}

// --- kernel 0b: tau = 10th-smallest slice-min; pack A-frags; zero cursors ---
__global__ __launch_bounds__(64) void k_tau(const float* __restrict__ minima,
                                            const float* __restrict__ obs,
                                            const float* __restrict__ act,
                                            v8s* __restrict__ afrag,
                                            int* __restrict__ cursor) {
    __shared__ __align__(16) unsigned short qs[48];
    const int b = blockIdx.x, lane = threadIdx.x;
    if (b == 0 && lane == 0) { cursor[0] = 0; cursor[1] = 0; }
    float v[16];
#pragma unroll
    for (int k = 0; k < 16; ++k) v[k] = minima[(size_t)b * SBLK + lane + 64 * k];
    float last = 0.f;
    for (int r = 0; r < TOPK; ++r) {
        float lm = v[0]; int la = 0;
#pragma unroll
        for (int k = 1; k < 16; ++k) { if (v[k] < lm) { lm = v[k]; la = k; } }
        float wm = lm;
        for (int off = 32; off; off >>= 1) wm = fminf(wm, __shfl_xor(wm, off));
        unsigned long long msk = __ballot(lm == wm);
        int first = (int)__builtin_ctzll(msk);
        if (lane == first) {
#pragma unroll
            for (int k = 0; k < 16; ++k) { if (k == la) v[k] = __builtin_inff(); }
        }
        last = wm;   // wave-uniform
    }
    // q-hat = [q(34), -0.5, (tau+MARGIN)/2, 0..0] as bf16 in LDS
    float val = 0.f;
    if (lane < 32)       val = obs[b * 32 + lane];
    else if (lane < 34)  val = act[b * 2 + (lane - 32)];
    else if (lane == 34) val = -0.5f;
    else if (lane == 35) val = 0.5f * (last + MARGIN);
    if (lane < 48) qs[lane] = (lane < 36) ? f2bf(val) : (unsigned short)0;
    __syncthreads();
    // pack A-frags: chunk (s,half) = q-hat shorts [s*16+half*8 .. +8]
    // dest lane-id in a filter wave = half*32 + mrow, query row = qt*32+mrow
    if (lane < 6) {
        int s = lane >> 1, half = lane & 1;
        int qt = b >> 5, mrow = b & 31;
        v8s frag = *(const v8s*)&qs[s * 16 + half * 8];
        afrag[(qt * 3 + s) * 64 + half * 32 + mrow] = frag;
    }
}

// --- kernel 1: MFMA bf16 filter; A-frags in LDS -> 3 waves/SIMD occupancy ---
// R10 counters (first direct read): 41.6us, VALUBusy 26%, MfmaUtil 10%, HBM
// 12%, Occupancy 19% — latency-bound at the MINIMUM possible TLP. A[8][3] in
// registers (96+ regs/wave) forces 2 waves/SIMD; any ~500cy gap in one wave
// idles the SIMD ~40% of the time — the structure-invariant plateau R1-R10
// measured. Fix: A-frags move to LDS (24KB/block, one-time copy; 3x
// ds_read_b128 per qt at lane-contiguous 16B stride = canonical conflict-free
// fragment read). Register footprint ~110 -> launch_bounds(256,3) fits with
// no spill -> 3 waves/SIMD (+50% TLP). Chunk loop stays vmem-store-free
// (R10's LDS overflow list kept). LDS/block ~42KB <= 53KB cap at 3 blocks.
__global__ __launch_bounds__(256, 3) void k_filter(const float* __restrict__ msa,
                                                   const v8s* __restrict__ afrag,
                                                   int* __restrict__ cursor,
                                                   unsigned* __restrict__ pbuf,
                                                   int* __restrict__ posq) {
    __shared__ __align__(16) v8s ALds[24 * 64];              // 24576 B
    __shared__ int lcount[NB];                               // 1024 B
    __shared__ int lcand[NB * LCAP];                         // 8192 B
    __shared__ unsigned ovf[OVFC];                           // 8192 B
    __shared__ int ovfn;
    __shared__ int gbase;
    const int g = blockIdx.x, t = threadIdx.x;
    const int w = t >> 6, lane = t & 63;
    const int mrow = lane & 31, half = lane >> 5;
    // one-time copy of all 24 A-fragments into LDS (global 16B -> LDS 16B)
    for (int i = t; i < 24 * 64; i += 256) ALds[i] = afrag[i];
    lcount[t] = 0;
    if (t == 0) ovfn = 0;
    __syncthreads();
    const v16f zacc = (v16f)0.0f;               // persistent zero C-input
    const int gw = g * 4 + w;                   // global wave id, < 3072
    const int step = FBLK * 4;                  // 3072

    // process one chunk from a register buffer (inlined; all indices static).
    // NO global-memory ops anywhere in here -> vmcnt stays countable.
    auto process = [&](const float2* c, int wc) {
        const int p0 = wc * 32 + mrow;
        // per-lane partial fp32 norm; lane pair (half0,half1) shares the row
        float n0 = 0.f, n1 = 0.f;
        n0 = fmaf(c[0].x, c[0].x, n0); n1 = fmaf(c[0].y, c[0].y, n1);
        n0 = fmaf(c[1].x, c[1].x, n0); n1 = fmaf(c[1].y, c[1].y, n1);
        n0 = fmaf(c[2].x, c[2].x, n0); n1 = fmaf(c[2].y, c[2].y, n1);
        n0 = fmaf(c[3].x, c[3].x, n0); n1 = fmaf(c[3].y, c[3].y, n1);
        n0 = fmaf(c[4].x, c[4].x, n0); n1 = fmaf(c[4].y, c[4].y, n1);
        n0 = fmaf(c[5].x, c[5].x, n0); n1 = fmaf(c[5].y, c[5].y, n1);
        n0 = fmaf(c[6].x, c[6].x, n0); n1 = fmaf(c[6].y, c[6].y, n1);
        n0 = fmaf(c[7].x, c[7].x, n0); n1 = fmaf(c[7].y, c[7].y, n1);
        float part = n0 + n1;
        part = fmaf(c[8].x, c[8].x * 0.5f, part);   // half of dims 32/33 per lane
        part = fmaf(c[8].y, c[8].y * 0.5f, part);
        float nrm = part + __shfl_xor(part, 32);
        float thr = 0.5f * nrm;                 // hit iff acc >= thr
        // B-frags: shufflevector-of-pk2 (proven no-spill) + literal-index B2
        v4s b0lo = __builtin_shufflevector(pk2(c[0]), pk2(c[1]), 0, 1, 2, 3);
        v4s b0hi = __builtin_shufflevector(pk2(c[2]), pk2(c[3]), 0, 1, 2, 3);
        v8s B0 = __builtin_shufflevector(b0lo, b0hi, 0, 1, 2, 3, 4, 5, 6, 7);
        v4s b1lo = __builtin_shufflevector(pk2(c[4]), pk2(c[5]), 0, 1, 2, 3);
        v4s b1hi = __builtin_shufflevector(pk2(c[6]), pk2(c[7]), 0, 1, 2, 3);
        v8s B1 = __builtin_shufflevector(b1lo, b1hi, 0, 1, 2, 3, 4, 5, 6, 7);
        v8s B2 = (v8s)(short)0;
        if (half == 0) {
            v2s m33 = pk2(c[8]);
            B2[0] = m33[0];                     // m32 (k=32)
            B2[1] = m33[1];                     // m33 (k=33)
            B2[3] = (short)0x3F80;              // k=35: 1.0 pairs q's tau-term
        }                                       // k=34 stays 0 (pairs q's -0.5)
#pragma unroll
        for (int qt = 0; qt < 8; ++qt) {
            v8s a0 = ALds[(qt * 3 + 0) * 64 + lane];   // ds_read_b128 x3,
            v8s a1 = ALds[(qt * 3 + 1) * 64 + lane];   // lane-contiguous 16B
            v8s a2 = ALds[(qt * 3 + 2) * 64 + lane];   // -> conflict-free
            v16f acc = __builtin_amdgcn_mfma_f32_32x32x16_bf16(a0, B0, zacc, 0, 0, 0);
            acc = __builtin_amdgcn_mfma_f32_32x32x16_bf16(a1, B1, acc, 0, 0, 0);
            acc = __builtin_amdgcn_mfma_f32_32x32x16_bf16(a2, B2, acc, 0, 0, 0);
            // 3-ary max tree (fuses to v_max3_f32): skip mask scan on no hit
            float m0 = fmaxf(fmaxf(acc[0], acc[1]), acc[2]);
            float m1 = fmaxf(fmaxf(acc[3], acc[4]), acc[5]);
            float m2 = fmaxf(fmaxf(acc[6], acc[7]), acc[8]);
            float m3 = fmaxf(fmaxf(acc[9], acc[10]), acc[11]);
            float m4 = fmaxf(fmaxf(acc[12], acc[13]), acc[14]);
            float mx = fmaxf(fmaxf(fmaxf(m0, m1), m2),
                             fmaxf(fmaxf(m3, m4), acc[15]));
            if (mx >= thr) {
                unsigned hm = 0;
#pragma unroll
                for (int r = 0; r < 16; ++r) hm |= (acc[r] >= thr) ? (1u << r) : 0u;
                while (hm) {                    // rare per lane; LDS-ONLY path
                    int r = __builtin_ctz(hm);
                    hm &= hm - 1;
                    int qq = qt * 32 + (r & 3) + 8 * (r >> 2) + 4 * half;
                    int slot = atomicAdd(&lcount[qq], 1);
                    if (slot < LCAP) lcand[qq * LCAP + slot] = p0;
                    else {                      // overflow -> per-block LDS list
                        int dg = atomicAdd(&ovfn, 1);
                        if (dg < OVFC) ovf[dg] = ((unsigned)qq << 19) | (unsigned)p0;
                    }
                }
            }
        }
    };

    float2 bufA[9], bufB[9];
    int wc = gw;                                 // gw < 3072 <= NWCH always
    load9(bufA, msa + (size_t)(wc * 32 + mrow) * 34, half);  // prologue
#pragma unroll 1
    for (;;) {
        const int w1 = wc + step;
        {   // prefetch next into B; sched_barrier pins issue BEFORE compute
            const int pn = (w1 < NWCH) ? w1 : gw;
            load9(bufB, msa + (size_t)(pn * 32 + mrow) * 34, half);
        }
        __builtin_amdgcn_sched_barrier(0);
        process(bufA, wc);
        wc = w1;
        if (wc >= NWCH) break;
        const int w2 = wc + step;
        {   // prefetch next into A
            const int pn = (w2 < NWCH) ? w2 : gw;
            load9(bufA, msa + (size_t)(pn * 32 + mrow) * 34, half);
        }
        __builtin_amdgcn_sched_barrier(0);
        process(bufB, wc);
        wc = w2;
        if (wc >= NWCH) break;
    }
    __syncthreads();
    // flush LDS overflow list to the global overflow region (usually empty)
    {
        int no = ovfn;
        if (no > OVFC) no = OVFC;
        for (int i = t; i < no; i += 256) {
            int dg = atomicAdd(cursor + 1, 1);
            if (dg < OCAP) pbuf[PMAIN + dg] = ovf[i];
        }
    }
    // flush: prefix-scan -> ONE cursor atomic -> compacted writes + pos table
    int n = lcount[t];
    if (n > LCAP) n = LCAP;
    lcount[t] = n;
    __syncthreads();
    for (int off = 1; off < 256; off <<= 1) {   // Hillis-Steele inclusive scan
        int v = (t >= off) ? lcount[t - off] : 0;
        __syncthreads();
        lcount[t] += v;
        __syncthreads();
    }
    int base_l = lcount[t] - n;
    if (t == 255) gbase = atomicAdd(cursor, lcount[255]);
    __syncthreads();
    int start = gbase + base_l;
    if (start >= PMAIN) { start = 0; n = 0; }
    else if (start + n > PMAIN) n = PMAIN - start;
    posq[g * NB + t] = start | (n << 20);       // coalesced, no atomic
    for (int i = 0; i < n; ++i)
        pbuf[start + i] = (unsigned)lcand[t * LCAP + i];
}

// --- kernel 2: gather my segments, exact fp32 rescore, top-10, softmax ------
__global__ __launch_bounds__(256) void k_final(const float* __restrict__ obs,
                                               const float* __restrict__ act,
                                               const float* __restrict__ msa,
                                               const unsigned* __restrict__ pbuf,
                                               const int* __restrict__ posq,
                                               const int* __restrict__ cursor,
                                               const float* __restrict__ memQ,
                                               float* __restrict__ out) {
    __shared__ float ls[CAP];
    __shared__ int   li[CAP];
    __shared__ int   sc[NB];
    __shared__ int   lcnt;
    __shared__ float rs[4];
    __shared__ int   ri[4];
    __shared__ float sel_s[TOPK];
    __shared__ int   sel_i[TOPK];
    const int b = blockIdx.x, t = threadIdx.x;
    const int lane = t & 63, wid = t >> 6;
    // gather my posq segments (FBLK = NSEG*256 -> NSEG fixed slots)
    int nk[NSEG], pk6[NSEG], tot = 0;
#pragma unroll
    for (int k = 0; k < NSEG; ++k) {
        int packed = posq[(size_t)(t + 256 * k) * NB + b];
        nk[k] = (packed >> 20) & 0xF;
        pk6[k] = packed & 0xFFFFF;
        tot += nk[k];
    }
    sc[t] = tot;
    __syncthreads();
    for (int off = 1; off < 256; off <<= 1) {   // prefix scan (no atomics)
        int v = (t >= off) ? sc[t - off] : 0;
        __syncthreads();
        sc[t] += v;
        __syncthreads();
    }
    int myoff = sc[t] - tot;
    if (t == 0) lcnt = (sc[255] > CAP) ? CAP : sc[255];
    __syncthreads();
#pragma unroll
    for (int k = 0; k < NSEG; ++k)
        for (int i = 0; i < nk[k]; ++i) {
            if (myoff < CAP) li[myoff] = (int)pbuf[pk6[k] + i];
            ++myoff;
        }
    // overflow region (normally empty)
    int novf = cursor[1];
    if (novf > OCAP) novf = OCAP;
    for (int j = t; j < novf; j += 256) {
        unsigned pr = pbuf[PMAIN + j];
        if ((int)(pr >> 19) == b) {
            int s = atomicAdd(&lcnt, 1);
            if (s < CAP) li[s] = (int)(pr & 0x7FFFFu);
        }
    }
    __syncthreads();
    int cnt = lcnt;
    if (cnt > CAP) cnt = CAP;
    float q[34];
    load_q(obs, act, b, q);
    for (int j = t; j < cnt; j += 256) {        // exact fp32 re-scores
        const float* row = msa + (size_t)li[j] * 34;
        ls[j] = fmaf(-2.f, dot34(row, q), norm34(row));
    }
    __syncthreads();
    for (int k = 0; k < TOPK; ++k) {
        float bs = __builtin_inff();
        int   bi = 0x7fffffff;
        for (int j = t; j < cnt; j += 256) {
            float s = ls[j]; int i = li[j];
            if (s < bs || (s == bs && i < bi)) { bs = s; bi = i; }
        }
        for (int off = 32; off; off >>= 1) {
            float s2 = __shfl_down(bs, off);
            int   i2 = __shfl_down(bi, off);
            if (s2 < bs || (s2 == bs && i2 < bi)) { bs = s2; bi = i2; }
        }
        if (lane == 0) { rs[wid] = bs; ri[wid] = bi; }
        __syncthreads();
        if (t == 0) {
            float fs = rs[0]; int fi = ri[0];
#pragma unroll
            for (int ww = 1; ww < 4; ++ww) {
                if (rs[ww] < fs || (rs[ww] == fs && ri[ww] < fi)) { fs = rs[ww]; fi = ri[ww]; }
            }
            sel_s[k] = fs; sel_i[k] = fi;
        }
        __syncthreads();
        const int win = sel_i[k];
        for (int j = t; j < cnt; j += 256) {
            if (li[j] == win) ls[j] = __builtin_inff();
        }
        __syncthreads();
    }
    if (t == 0) {
        float m = sel_s[TOPK - 1];
        float wsum = 0.f, acc = 0.f;
#pragma unroll
        for (int k = 0; k < TOPK; ++k) {
            if (sel_i[k] == 0x7fffffff) continue;
            float w2 = expf(sel_s[k] - m);
            wsum += w2;
            acc = fmaf(w2, memQ[sel_i[k]], acc);
        }
        out[b] = acc / wsum;
    }
}

extern "C" void kernel_launch(void* const* d_in, const int* in_sizes, int n_in,
                              void* d_out, int out_size, void* d_ws, size_t ws_size,
                              hipStream_t stream) {
    const float* obs = (const float*)d_in[0];   // [256,32]
    const float* act = (const float*)d_in[1];   // [256,2]
    const float* msa = (const float*)d_in[2];   // [500000,34]
    const float* mq  = (const float*)d_in[3];   // [500000,1]
    float* out = (float*)d_out;                 // [256]

    char* ws = (char*)d_ws;
    int*      cursor = (int*)ws;                            // 8 B
    v8s*      afrag  = (v8s*)(ws + 256);                    // 24576 B
    float*    minima = (float*)(ws + 32768);                // 1 MB (256 x 1024)
    int*      posq   = (int*)(ws + 32768 + 1048576);        // 786 KB used
    unsigned* pbuf   = (unsigned*)(ws + 32768 + 1048576 + 1572864); // 1703936 B
    // total ws use ~4.3 MB

    k_sample<<<SBLK, 256, 0, stream>>>(obs, act, msa, minima);
    k_tau   <<<NB, 64, 0, stream>>>(minima, obs, act, afrag, cursor);
    k_filter<<<FBLK, 256, 0, stream>>>(msa, afrag, cursor, pbuf, posq);
    k_final <<<NB, 256, 0, stream>>>(obs, act, msa, pbuf, posq, cursor, mq, out);
}